// Round 5
// baseline (107.564 us; speedup 1.0000x reference)
//
#include <hip/hip_runtime.h>
#include <stdint.h>

// Problem: B,T,C = 2,768,64; N_HEAD=64 -> head_dim=1; fp32 buffers.
// R4 lesson: two-kernel (ws + s_load) design pays inter-kernel L2-flush and
// unverified scalarization; fuse everything, keep k/v in LDS, lane-per-row
// attention with wave-uniform broadcast ds_read_b128 (2 j per DS instr).
constexpr int Tc = 768;
constexpr int Hc = 64;
constexpr int Bc = 2;
constexpr float LOG2E = 1.44269504088896f;

typedef float v2f __attribute__((ext_vector_type(2)));
typedef float v4f __attribute__((ext_vector_type(4)));

// grid (12,64,2) = 1536 blocks = 6 blocks/CU exact; block = 64 query rows,
// 4 waves = 4 j-quarters (192 j each). 24 waves/CU, LDS 8.2 KB/block.
__global__ __launch_bounds__(256, 6) void attn_one_kernel(
    const float* __restrict__ x,      // (B,T,64)
    const float* __restrict__ W,      // (128,64): [0,64)=Wq, [64,128)=Wk
    const float* __restrict__ vtmp,   // (64)
    const float* __restrict__ ptmp,   // (64)
    float* __restrict__ out)          // (B,T,64)
{
    const int tid  = threadIdx.x;
    const int lane = tid & 63;
    const int qtr  = __builtin_amdgcn_readfirstlane(tid >> 6);
    const int rt   = blockIdx.x;   // row tile 0..11
    const int h    = blockIdx.y;
    const int b    = blockIdx.z;

    __shared__ float kv[2 * Tc];            // interleaved {k[t], v[t]} -> b128 = 2 j
    __shared__ float psum[4][64], pacc[4][64];

    const float* xb = x + (size_t)b * Tc * 64;
    // wave-uniform weight rows -> scalar s_loads (verified R3: SGPR_Count 96)
    const float* __restrict__ wq = W + h * 64;
    const float* __restrict__ wk = W + (64 + h) * 64;
    const float vp = vtmp[h] * ptmp[h];     // fold proj scale into v

    // ---- stage k,v for all 768 positions (3 rows/thread, coalesced) ----
#pragma unroll
    for (int r = 0; r < 3; ++r) {
        const int t = tid + 256 * r;
        const v4f* row = (const v4f*)(xb + (size_t)t * 64);
        float ak = 0.f;
#pragma unroll 4
        for (int c = 0; c < 16; ++c) {
            v4f u = row[c];
            ak = fmaf(u.x, wk[4 * c + 0], ak);
            ak = fmaf(u.y, wk[4 * c + 1], ak);
            ak = fmaf(u.z, wk[4 * c + 2], ak);
            ak = fmaf(u.w, wk[4 * c + 3], ak);
        }
        v2f kvw; kvw.x = ak; kvw.y = xb[(size_t)t * 64 + h] * vp;
        *(v2f*)&kv[2 * t] = kvw;            // ds_write_b64, 2-way bank alias (free)
    }

    // ---- q for this wave's row (kept in a register; 4x wave-redundant, cheap) ----
    const int i = rt * 64 + lane;
    float q;
    {
        const v4f* row = (const v4f*)(xb + (size_t)i * 64);
        float aq = 0.f;
#pragma unroll 4
        for (int c = 0; c < 16; ++c) {
            v4f u = row[c];
            aq = fmaf(u.x, wq[4 * c + 0], aq);
            aq = fmaf(u.y, wq[4 * c + 1], aq);
            aq = fmaf(u.z, wq[4 * c + 2], aq);
            aq = fmaf(u.w, wq[4 * c + 3], aq);
        }
        q = aq * LOG2E;
    }
    __syncthreads();

    // ---- attention: lane owns row i; this wave covers j in [j0, j0+192) ----
    // slopes[h] = 2^(-(h+1)/8) (H=64), folded with log2(e)
    const float slope2 = exp2f(-0.125f * (float)(h + 1)) * LOG2E;
    const int j0 = qtr * (Tc / 4);
    v2f dj;                                  // slope2*(j-i) for {j, j+1}
    dj.x = slope2 * (float)(j0 - i);
    dj.y = slope2 * (float)(j0 + 1 - i);
    const float step = slope2 * 2.f;
    v2f sum = {0.f, 0.f}, acc = {0.f, 0.f};

    const v4f* __restrict__ kvp = (const v4f*)&kv[2 * j0];  // 16B-aligned
#pragma unroll 8
    for (int g = 0; g < (Tc / 4) / 2; ++g) { // 96 groups x 2 j
        v4f kk = kvp[g];                     // broadcast ds_read_b128: k0,v0,k1,v1
        v2f bias;
        bias.x = fminf(dj.x, 0.f);           // slope*min(j-i,0)
        bias.y = fminf(dj.y, 0.f);
        v2f sc;
        sc.x = fmaf(q, kk.x, bias.x);
        sc.y = fmaf(q, kk.z, bias.y);
        v2f e;
        e.x = __builtin_amdgcn_exp2f(sc.x);  // scores bounded, bias<=0: no max-sub
        e.y = __builtin_amdgcn_exp2f(sc.y);
        sum += e;                            // v_pk_add_f32
        acc.x = fmaf(e.x, kk.y, acc.x);
        acc.y = fmaf(e.y, kk.w, acc.y);
        dj += (v2f){step, step};             // v_pk_add_f32
    }
    psum[qtr][lane] = sum.x + sum.y;
    pacc[qtr][lane] = acc.x + acc.y;
    __syncthreads();

    // ---- combine 4 j-quarters, write out (t-major layout => strided store) ----
    if (tid < 64) {
        float s = psum[0][lane] + psum[1][lane] + psum[2][lane] + psum[3][lane];
        float a = pacc[0][lane] + pacc[1][lane] + pacc[2][lane] + pacc[3][lane];
        out[((size_t)(b * Tc + rt * 64 + lane)) * 64 + h] =
            a * __builtin_amdgcn_rcpf(s);
    }
}

extern "C" void kernel_launch(void* const* d_in, const int* in_sizes, int n_in,
                              void* d_out, int out_size, void* d_ws, size_t ws_size,
                              hipStream_t stream) {
    const float* x    = (const float*)d_in[0];
    const float* W    = (const float*)d_in[1];
    const float* vtmp = (const float*)d_in[2];
    const float* ptmp = (const float*)d_in[3];
    float* out = (float*)d_out;

    attn_one_kernel<<<dim3(12, Hc, Bc), 256, 0, stream>>>(x, W, vtmp, ptmp, out);
}

// Round 6
// 89.711 us; speedup vs baseline: 1.1990x; 1.1990x over previous
//
#include <hip/hip_runtime.h>
#include <stdint.h>

// Problem: B,T,C = 2,768,64; N_HEAD=64 -> head_dim=1; fp32 buffers.
// R5 lesson: fused designs lose to split (per-block k/v recompute dominates).
// Split design, measured best (R4, ~32 us kernels): improve both kernels.
//   - proj: 384 blocks (was 96), one head per wave.
//   - attn: lane-per-j, k/v register-cached from ws (zero in-loop memory),
//     uniform s_load q per row, DPP reduction (verified R3), zero LDS.
// Harness overhead is a measured-constant ~52 us (268MB ws poison fill etc.)
// -> dur ~= 52 + sum(kernels).
constexpr int Tc = 768;
constexpr int Hc = 64;
constexpr int Bc = 2;
constexpr float LOG2E = 1.44269504088896f;
constexpr size_t SLAB = (size_t)Bc * Hc * Tc;   // 98304 floats per slab

typedef float v4f __attribute__((ext_vector_type(4)));

// ---------------------------------------------------------------------------
// Kernel 1: projection into transposed slabs (contiguous in t per (b,h)):
//   qs[(b*64+h)*768+t] = LOG2E * dot(x[b,t,:], Wq[h,:])
//   ks[..]             = dot(x[b,t,:], Wk[h,:])
//   vs[..]             = x[b,t,h] * vtmp[h] * ptmp[h]
// grid (24 row-tiles, 16 h-groups) x 256 = 384 blocks; lane owns one row,
// wave owns one head (wave-uniform -> W rows via s_load).
// ---------------------------------------------------------------------------
__global__ __launch_bounds__(256) void proj_kernel(
    const float* __restrict__ x, const float* __restrict__ W,
    const float* __restrict__ vtmp, const float* __restrict__ ptmp,
    float* __restrict__ qs, float* __restrict__ ks, float* __restrict__ vs)
{
    const int lane = threadIdx.x & 63;
    const int w    = __builtin_amdgcn_readfirstlane(threadIdx.x >> 6);
    const int g    = blockIdx.x * 64 + lane;     // global row in [0,1536)
    const int bh0  = (g / Tc) * Hc;              // b*64 (64 | 768: no straddle)
    const int t    = g % Tc;
    const int h    = blockIdx.y * 4 + w;         // wave-uniform head

    float xr[64];
    const v4f* xp = (const v4f*)(x + (size_t)g * 64);
#pragma unroll
    for (int c = 0; c < 16; ++c) ((v4f*)xr)[c] = xp[c];

    const float* __restrict__ wq = W + h * 64;
    const float* __restrict__ wk = W + (64 + h) * 64;
    float aq = 0.f, ak = 0.f;
#pragma unroll
    for (int c = 0; c < 64; ++c) {
        aq = fmaf(xr[c], wq[c], aq);
        ak = fmaf(xr[c], wk[c], ak);
    }
    const size_t o = (size_t)(bh0 + h) * Tc + t;   // lane-coalesced
    qs[o] = aq * LOG2E;
    ks[o] = ak;
    vs[o] = xr[h] * vtmp[h] * ptmp[h];
}

// 64-lane sum via DPP (VALU pipe, no LDS). Total lands in lane 63.
__device__ __forceinline__ float dpp_reduce_add(float v) {
    v += __int_as_float(__builtin_amdgcn_update_dpp(0, __float_as_int(v), 0x111, 0xf, 0xf, true));
    v += __int_as_float(__builtin_amdgcn_update_dpp(0, __float_as_int(v), 0x112, 0xf, 0xf, true));
    v += __int_as_float(__builtin_amdgcn_update_dpp(0, __float_as_int(v), 0x114, 0xf, 0xf, true));
    v += __int_as_float(__builtin_amdgcn_update_dpp(0, __float_as_int(v), 0x118, 0xf, 0xf, true));
    v += __int_as_float(__builtin_amdgcn_update_dpp(0, __float_as_int(v), 0x142, 0xf, 0xf, true));
    v += __int_as_float(__builtin_amdgcn_update_dpp(0, __float_as_int(v), 0x143, 0xf, 0xf, true));
    return v;
}

// ---------------------------------------------------------------------------
// Kernel 2: attention, lane-per-j. Lane caches k,v for j = lane+64r (r<12)
// in registers (one-time coalesced loads); per row: q via uniform s_load,
// 12 exp-fma groups, DPP reduce, lane63 stores. Zero LDS, zero in-loop VMEM.
// grid (12,64,2) = 1536 blocks = 6/CU, 4 waves x 16 rows per block.
// ---------------------------------------------------------------------------
__global__ __launch_bounds__(256, 6) void attn_kernel(
    const float* __restrict__ qs, const float* __restrict__ ks,
    const float* __restrict__ vs, float* __restrict__ out)
{
    const int lane = threadIdx.x & 63;
    const int w    = __builtin_amdgcn_readfirstlane(threadIdx.x >> 6);
    const int rt   = blockIdx.x;   // 0..11
    const int h    = blockIdx.y;
    const int b    = blockIdx.z;
    const int bh   = b * Hc + h;

    // slopes[h] = 2^(-(h+1)/8) (H=64), folded with log2(e)
    const float slope2 = exp2f(-0.125f * (float)(h + 1)) * LOG2E;

    const float* __restrict__ kp = ks + (size_t)bh * Tc;
    const float* __restrict__ vp = vs + (size_t)bh * Tc;
    const float* __restrict__ qp = qs + (size_t)bh * Tc;

    float kr[12], vr[12], bj[12];
#pragma unroll
    for (int r = 0; r < 12; ++r) {
        const int j = lane + 64 * r;      // coalesced
        kr[r] = kp[j];
        vr[r] = vp[j];
        bj[r] = slope2 * (float)j;
    }

    const int i0 = rt * 64 + w * 16;      // this wave's 16 rows
#pragma unroll 2
    for (int ii = 0; ii < 16; ++ii) {
        const int i  = i0 + ii;
        const float q  = qp[i];           // uniform address -> s_load
        const float si = slope2 * (float)i;
        float sum = 0.f, acc = 0.f;
        // scores bounded (|q.k| small, bias <= 0): no max-subtraction needed
#pragma unroll
        for (int r = 0; r < 12; ++r) {
            float d = fminf(bj[r] - si, 0.f);            // slope*min(j-i,0)
            float e = __builtin_amdgcn_exp2f(fmaf(q, kr[r], d));
            sum += e;
            acc  = fmaf(e, vr[r], acc);
        }
        sum = dpp_reduce_add(sum);
        acc = dpp_reduce_add(acc);
        if (lane == 63) {
            out[((size_t)(b * Tc + i)) * 64 + h] = acc * __builtin_amdgcn_rcpf(sum);
        }
    }
}

extern "C" void kernel_launch(void* const* d_in, const int* in_sizes, int n_in,
                              void* d_out, int out_size, void* d_ws, size_t ws_size,
                              hipStream_t stream) {
    const float* x    = (const float*)d_in[0];
    const float* W    = (const float*)d_in[1];
    const float* vtmp = (const float*)d_in[2];
    const float* ptmp = (const float*)d_in[3];
    float* out = (float*)d_out;

    float* qsl = (float*)d_ws;
    float* ksl = qsl + SLAB;
    float* vsl = ksl + SLAB;

    proj_kernel<<<dim3(24, 16), 256, 0, stream>>>(x, W, vtmp, ptmp, qsl, ksl, vsl);
    attn_kernel<<<dim3(12, Hc, Bc), 256, 0, stream>>>(qsl, ksl, vsl, out);
}